// Round 1
// baseline (46678.824 us; speedup 1.0000x reference)
//
#include <hip/hip_runtime.h>
#include <cstddef>

#define NMOD 64
#define HID 512
#define TSTEPS 1024
#define G4 (4 * HID)  // 2048 gate rows per module

// sigmoid / tanh via fast exp; saturate correctly at +-inf
__device__ __forceinline__ float fsigmoid(float x) {
    return 1.0f / (1.0f + __expf(-x));
}
__device__ __forceinline__ float ftanh(float x) {
    // tanh(x) = 1 - 2/(exp(2x)+1); stable for all x
    return 1.0f - 2.0f / (__expf(2.0f * x) + 1.0f);
}

// One block per module. 1024 threads: 64 row-groups of 16 lanes.
// Per step: gates[r] = hist[t]*W_ih[r] + (b_ih+b_hh)[r] + dot(h, W_hh[r,:])
// W_hh streamed from global (L2/L3); h, gates in LDS; c in registers of tid<512.
__global__ __launch_bounds__(1024) void lstm_module_kernel(
    const float* __restrict__ recent,   // [64]
    const float* __restrict__ history,  // [64,1024]
    const float* __restrict__ W_ih,     // [64,2048]
    const float* __restrict__ W_hh,     // [64,2048,512]
    const float* __restrict__ b_ih,     // [64,2048]
    const float* __restrict__ b_hh,     // [64,2048]
    const float* __restrict__ lin_W,    // [64,513]
    const float* __restrict__ lin_b,    // [64]
    float* __restrict__ per_mod)        // ws [64]
{
    const int n = blockIdx.x;
    const int tid = threadIdx.x;

    __shared__ float h_sh[HID];
    __shared__ float gates_sh[G4];
    __shared__ float wib_sh[G4];
    __shared__ float bias_sh[G4];
    __shared__ float hist_sh[TSTEPS];

    // Stage per-module constants into LDS
    for (int i = tid; i < G4; i += 1024) {
        wib_sh[i]  = W_ih[(size_t)n * G4 + i];
        bias_sh[i] = b_ih[(size_t)n * G4 + i] + b_hh[(size_t)n * G4 + i];
    }
    for (int i = tid; i < TSTEPS; i += 1024) hist_sh[i] = history[(size_t)n * TSTEPS + i];
    if (tid < HID) h_sh[tid] = 0.0f;
    float c_reg = 0.0f;
    __syncthreads();

    const int sub = tid & 15;   // lane within 16-lane row group
    const int rid = tid >> 4;   // row group 0..63
    const float* Wbase = W_hh + (size_t)n * G4 * HID;

    for (int t = 0; t < TSTEPS; ++t) {
        const float x = hist_sh[t];

        // Preload this lane's 32 h values (positions fixed per lane, reused
        // for all 32 row passes). 16 lanes x float4 = 256B coalesced LDS reads;
        // groups within a wave read identical addresses -> broadcast, free.
        float hreg[32];
        #pragma unroll
        for (int j = 0; j < 8; ++j) {
            const float4 hv = *reinterpret_cast<const float4*>(&h_sh[sub * 4 + j * 64]);
            hreg[4 * j + 0] = hv.x;
            hreg[4 * j + 1] = hv.y;
            hreg[4 * j + 2] = hv.z;
            hreg[4 * j + 3] = hv.w;
        }

        // 2048 rows / (1024 threads / 16 lanes-per-row) = 32 passes
        for (int p = 0; p < 32; ++p) {
            const int r = p * 64 + rid;
            const float* wr = Wbase + (size_t)r * HID + sub * 4;
            float acc = 0.0f;
            #pragma unroll
            for (int j = 0; j < 8; ++j) {
                const float4 w = *reinterpret_cast<const float4*>(wr + j * 64);
                acc += w.x * hreg[4 * j + 0];
                acc += w.y * hreg[4 * j + 1];
                acc += w.z * hreg[4 * j + 2];
                acc += w.w * hreg[4 * j + 3];
            }
            // reduce across the 16 lanes of the row group
            acc += __shfl_xor(acc, 1, 64);
            acc += __shfl_xor(acc, 2, 64);
            acc += __shfl_xor(acc, 4, 64);
            acc += __shfl_xor(acc, 8, 64);
            if (sub == 0) gates_sh[r] = acc + x * wib_sh[r] + bias_sh[r];
        }
        __syncthreads();

        // Elementwise LSTM cell update; c lives in registers of tid<512
        if (tid < HID) {
            const float ig = fsigmoid(gates_sh[tid]);
            const float fg = fsigmoid(gates_sh[HID + tid]);
            const float gg = ftanh(gates_sh[2 * HID + tid]);
            const float og = fsigmoid(gates_sh[3 * HID + tid]);
            c_reg = fg * c_reg + ig * gg;
            h_sh[tid] = og * ftanh(c_reg);
        }
        __syncthreads();
    }

    // per-module linear: dot(h, lin_W[n,0:512]) + recent*lin_W[n,512] + lin_b[n]
    if (tid < HID) {
        float v = h_sh[tid] * lin_W[(size_t)n * (HID + 1) + tid];
        #pragma unroll
        for (int m = 32; m; m >>= 1) v += __shfl_xor(v, m, 64);
        if ((tid & 63) == 0) gates_sh[tid >> 6] = v;
    }
    __syncthreads();
    if (tid == 0) {
        float s = 0.0f;
        #pragma unroll
        for (int w = 0; w < HID / 64; ++w) s += gates_sh[w];
        s += recent[n] * lin_W[(size_t)n * (HID + 1) + HID] + lin_b[n];
        per_mod[n] = s;
    }
}

__global__ void finish_kernel(const float* __restrict__ per_mod,
                              const float* __restrict__ final_W,
                              const float* __restrict__ final_b,
                              float* __restrict__ out)
{
    const int l = threadIdx.x;  // 64 threads
    float v = per_mod[l] * final_W[l];
    #pragma unroll
    for (int m = 32; m; m >>= 1) v += __shfl_xor(v, m, 64);
    if (l == 0) out[0] = v + final_b[0];
}

extern "C" void kernel_launch(void* const* d_in, const int* in_sizes, int n_in,
                              void* d_out, int out_size, void* d_ws, size_t ws_size,
                              hipStream_t stream) {
    const float* recent  = (const float*)d_in[0];
    const float* history = (const float*)d_in[1];
    const float* W_ih    = (const float*)d_in[2];
    const float* W_hh    = (const float*)d_in[3];
    const float* b_ih    = (const float*)d_in[4];
    const float* b_hh    = (const float*)d_in[5];
    const float* lin_W   = (const float*)d_in[6];
    const float* lin_b   = (const float*)d_in[7];
    const float* final_W = (const float*)d_in[8];
    const float* final_b = (const float*)d_in[9];
    float* out = (float*)d_out;
    float* per_mod = (float*)d_ws;  // 64 floats

    lstm_module_kernel<<<NMOD, 1024, 0, stream>>>(
        recent, history, W_ih, W_hh, b_ih, b_hh, lin_W, lin_b, per_mod);
    finish_kernel<<<1, 64, 0, stream>>>(per_mod, final_W, final_b, out);
}

// Round 2
// 39904.333 us; speedup vs baseline: 1.1698x; 1.1698x over previous
//
#include <hip/hip_runtime.h>
#include <hip/hip_fp16.h>
#include <cstddef>

#define NMOD 64
#define HID 512
#define TSTEPS 1024
#define G4 (4 * HID)      // 2048 gate rows per module
#define SEG 128           // h elements per block (multi-block path)
#define ROWS 512          // gate rows per block (4 quadrants x 128)

// ws layout (multi-block path)
#define WOFF_PERMOD 0           // 64 f32
#define WOFF_CTR    1024        // 64 counters, stride 16 u32
#define WOFF_H      8192        // 2 * 64 * 512 f32 = 262144 B
#define WOFF_W16    524288      // 64*2048*512 f16 = 134217728 B
#define W16_BYTES   ((size_t)NMOD * G4 * HID * 2)
#define WS_NEED     (WOFF_W16 + W16_BYTES)

__device__ __forceinline__ float fsigmoid(float x) {
    return 1.0f / (1.0f + __expf(-x));
}
__device__ __forceinline__ float ftanh(float x) {
    return 1.0f - 2.0f / (__expf(2.0f * x) + 1.0f);
}

// ---------------- f32 -> f16 weight conversion (every call; deterministic) ----
__global__ __launch_bounds__(256) void conv_kernel(const float* __restrict__ src,
                                                   __half* __restrict__ dst) {
    const size_t i = ((size_t)blockIdx.x * 256 + threadIdx.x) * 8;
    const float4 a = *reinterpret_cast<const float4*>(src + i);
    const float4 b = *reinterpret_cast<const float4*>(src + i + 4);
    __half2 h0 = __floats2half2_rn(a.x, a.y);
    __half2 h1 = __floats2half2_rn(a.z, a.w);
    __half2 h2 = __floats2half2_rn(b.x, b.y);
    __half2 h3 = __floats2half2_rn(b.z, b.w);
    uint4 o;
    o.x = *reinterpret_cast<unsigned*>(&h0);
    o.y = *reinterpret_cast<unsigned*>(&h1);
    o.z = *reinterpret_cast<unsigned*>(&h2);
    o.w = *reinterpret_cast<unsigned*>(&h3);
    *reinterpret_cast<uint4*>(dst + i) = o;
}

// ---------------- multi-block LSTM: 4 blocks per module, 1024 thr each -------
// Block b of module m owns h elements [b*128,(b+1)*128) i.e. gate rows
// q*512 + b*128 + j for q in 0..3. Per-step 4-block barrier via device-scope
// atomic counter; h double-buffered in global memory.
__global__ __launch_bounds__(1024) void lstm_mb_kernel(
    const float* __restrict__ recent,
    const float* __restrict__ history,
    const float* __restrict__ W_ih,
    const float* __restrict__ b_ih,
    const float* __restrict__ b_hh,
    const float* __restrict__ lin_W,
    const float* __restrict__ lin_b,
    const __half* __restrict__ w16,     // [64,2048,512] f16
    float* h_buf_,                      // [2,64,512] f32, zeroed
    unsigned* ctr,                      // [64*16] u32, zeroed
    float* __restrict__ per_mod)        // [64]
{
    const int m = blockIdx.x >> 2;
    const int b = blockIdx.x & 3;
    const int tid = threadIdx.x;

    __shared__ float h_lds[HID];
    __shared__ float gates_sh[ROWS];   // local layout [q*128 + j]
    __shared__ float wib_sh[ROWS];
    __shared__ float bias_sh[ROWS];
    __shared__ float hist_sh[TSTEPS];
    __shared__ float red_sh[8];

    volatile float* hb = h_buf_;

    for (int l = tid; l < ROWS; l += 1024) {
        const int q = l >> 7, j = l & 127;
        const size_t gr = (size_t)m * G4 + q * HID + b * SEG + j;
        wib_sh[l]  = W_ih[gr];
        bias_sh[l] = b_ih[gr] + b_hh[gr];
    }
    for (int i = tid; i < TSTEPS; i += 1024)
        hist_sh[i] = history[(size_t)m * TSTEPS + i];
    if (tid < HID) h_lds[tid] = 0.0f;
    float c_reg = 0.0f;   // live in tid<128
    __syncthreads();

    const int sub = tid & 15;   // lane within 16-lane row group
    const int rg  = tid >> 4;   // row group 0..63
    const __half* wblk = w16 + (size_t)m * G4 * HID;

    for (int t = 0; t < TSTEPS; ++t) {
        const float x = hist_sh[t];

        // preload this lane's 32 h values (columns sub*8+k+128*jj), reused all passes
        float hreg[32];
        #pragma unroll
        for (int jj = 0; jj < 4; ++jj) {
            const float4 a = *reinterpret_cast<const float4*>(&h_lds[jj * 128 + sub * 8]);
            const float4 c = *reinterpret_cast<const float4*>(&h_lds[jj * 128 + sub * 8 + 4]);
            hreg[jj * 8 + 0] = a.x; hreg[jj * 8 + 1] = a.y;
            hreg[jj * 8 + 2] = a.z; hreg[jj * 8 + 3] = a.w;
            hreg[jj * 8 + 4] = c.x; hreg[jj * 8 + 5] = c.y;
            hreg[jj * 8 + 6] = c.z; hreg[jj * 8 + 7] = c.w;
        }

        // 512 rows, 64 row-groups per pass -> 8 passes
        for (int pass = 0; pass < 8; ++pass) {
            const int l = pass * 64 + rg;
            const int q = l >> 7, j = l & 127;
            const __half* wr = wblk + ((size_t)(q * HID + b * SEG + j)) * HID;
            float acc = 0.0f;
            #pragma unroll
            for (int jj = 0; jj < 4; ++jj) {
                const uint4 wv = *reinterpret_cast<const uint4*>(wr + jj * 128 + sub * 8);
                const __half2* hw = reinterpret_cast<const __half2*>(&wv);
                float2 f;
                f = __half22float2(hw[0]); acc += f.x * hreg[jj*8+0] + f.y * hreg[jj*8+1];
                f = __half22float2(hw[1]); acc += f.x * hreg[jj*8+2] + f.y * hreg[jj*8+3];
                f = __half22float2(hw[2]); acc += f.x * hreg[jj*8+4] + f.y * hreg[jj*8+5];
                f = __half22float2(hw[3]); acc += f.x * hreg[jj*8+6] + f.y * hreg[jj*8+7];
            }
            acc += __shfl_xor(acc, 1, 64);
            acc += __shfl_xor(acc, 2, 64);
            acc += __shfl_xor(acc, 4, 64);
            acc += __shfl_xor(acc, 8, 64);
            if (sub == 0) gates_sh[l] = acc + x * wib_sh[l] + bias_sh[l];
        }
        __syncthreads();

        // elementwise cell update for my 128 elements
        if (tid < SEG) {
            const float ig = fsigmoid(gates_sh[tid]);
            const float fg = fsigmoid(gates_sh[SEG + tid]);
            const float gg = ftanh(gates_sh[2 * SEG + tid]);
            const float og = fsigmoid(gates_sh[3 * SEG + tid]);
            c_reg = fg * c_reg + ig * gg;
            const float hnew = og * ftanh(c_reg);
            hb[(size_t)((t + 1) & 1) * (NMOD * HID) + m * HID + b * SEG + tid] = hnew;
        }
        __syncthreads();   // drains vmcnt: all h stores issued & complete in L2

        if (tid == 0) {
            __threadfence();   // push stores to device coherence point
            __hip_atomic_fetch_add(&ctr[m * 16], 1u, __ATOMIC_RELEASE,
                                   __HIP_MEMORY_SCOPE_AGENT);
            const unsigned tgt = 4u * (unsigned)(t + 1);
            while (__hip_atomic_load(&ctr[m * 16], __ATOMIC_ACQUIRE,
                                     __HIP_MEMORY_SCOPE_AGENT) < tgt) {}
            __threadfence();   // invalidate stale cached h
        }
        __syncthreads();

        if (tid < HID)
            h_lds[tid] = hb[(size_t)((t + 1) & 1) * (NMOD * HID) + m * HID + tid];
        __syncthreads();
    }

    // per-module linear (block b==0 only); final h is in h_lds
    if (b == 0) {
        if (tid < HID) {
            float v = h_lds[tid] * lin_W[(size_t)m * (HID + 1) + tid];
            #pragma unroll
            for (int s2 = 32; s2; s2 >>= 1) v += __shfl_xor(v, s2, 64);
            if ((tid & 63) == 0) red_sh[tid >> 6] = v;
        }
        __syncthreads();
        if (tid == 0) {
            float s = 0.0f;
            #pragma unroll
            for (int w = 0; w < 8; ++w) s += red_sh[w];
            s += recent[m] * lin_W[(size_t)m * (HID + 1) + HID] + lin_b[m];
            per_mod[m] = s;
        }
    }
}

// ---------------- fallback: round-1 f32 single-block-per-module kernel -------
__global__ __launch_bounds__(1024) void lstm_module_kernel(
    const float* __restrict__ recent,
    const float* __restrict__ history,
    const float* __restrict__ W_ih,
    const float* __restrict__ W_hh,
    const float* __restrict__ b_ih,
    const float* __restrict__ b_hh,
    const float* __restrict__ lin_W,
    const float* __restrict__ lin_b,
    float* __restrict__ per_mod)
{
    const int n = blockIdx.x;
    const int tid = threadIdx.x;

    __shared__ float h_sh[HID];
    __shared__ float gates_sh[G4];
    __shared__ float wib_sh[G4];
    __shared__ float bias_sh[G4];
    __shared__ float hist_sh[TSTEPS];

    for (int i = tid; i < G4; i += 1024) {
        wib_sh[i]  = W_ih[(size_t)n * G4 + i];
        bias_sh[i] = b_ih[(size_t)n * G4 + i] + b_hh[(size_t)n * G4 + i];
    }
    for (int i = tid; i < TSTEPS; i += 1024) hist_sh[i] = history[(size_t)n * TSTEPS + i];
    if (tid < HID) h_sh[tid] = 0.0f;
    float c_reg = 0.0f;
    __syncthreads();

    const int sub = tid & 15;
    const int rid = tid >> 4;
    const float* Wbase = W_hh + (size_t)n * G4 * HID;

    for (int t = 0; t < TSTEPS; ++t) {
        const float x = hist_sh[t];
        float hreg[32];
        #pragma unroll
        for (int j = 0; j < 8; ++j) {
            const float4 hv = *reinterpret_cast<const float4*>(&h_sh[sub * 4 + j * 64]);
            hreg[4 * j + 0] = hv.x; hreg[4 * j + 1] = hv.y;
            hreg[4 * j + 2] = hv.z; hreg[4 * j + 3] = hv.w;
        }
        for (int p = 0; p < 32; ++p) {
            const int r = p * 64 + rid;
            const float* wr = Wbase + (size_t)r * HID + sub * 4;
            float acc = 0.0f;
            #pragma unroll
            for (int j = 0; j < 8; ++j) {
                const float4 w = *reinterpret_cast<const float4*>(wr + j * 64);
                acc += w.x * hreg[4*j+0] + w.y * hreg[4*j+1]
                     + w.z * hreg[4*j+2] + w.w * hreg[4*j+3];
            }
            acc += __shfl_xor(acc, 1, 64);
            acc += __shfl_xor(acc, 2, 64);
            acc += __shfl_xor(acc, 4, 64);
            acc += __shfl_xor(acc, 8, 64);
            if (sub == 0) gates_sh[r] = acc + x * wib_sh[r] + bias_sh[r];
        }
        __syncthreads();
        if (tid < HID) {
            const float ig = fsigmoid(gates_sh[tid]);
            const float fg = fsigmoid(gates_sh[HID + tid]);
            const float gg = ftanh(gates_sh[2 * HID + tid]);
            const float og = fsigmoid(gates_sh[3 * HID + tid]);
            c_reg = fg * c_reg + ig * gg;
            h_sh[tid] = og * ftanh(c_reg);
        }
        __syncthreads();
    }

    if (tid < HID) {
        float v = h_sh[tid] * lin_W[(size_t)n * (HID + 1) + tid];
        #pragma unroll
        for (int m2 = 32; m2; m2 >>= 1) v += __shfl_xor(v, m2, 64);
        if ((tid & 63) == 0) gates_sh[tid >> 6] = v;
    }
    __syncthreads();
    if (tid == 0) {
        float s = 0.0f;
        #pragma unroll
        for (int w = 0; w < HID / 64; ++w) s += gates_sh[w];
        s += recent[n] * lin_W[(size_t)n * (HID + 1) + HID] + lin_b[n];
        per_mod[n] = s;
    }
}

__global__ void finish_kernel(const float* __restrict__ per_mod,
                              const float* __restrict__ final_W,
                              const float* __restrict__ final_b,
                              float* __restrict__ out)
{
    const int l = threadIdx.x;
    float v = per_mod[l] * final_W[l];
    #pragma unroll
    for (int m = 32; m; m >>= 1) v += __shfl_xor(v, m, 64);
    if (l == 0) out[0] = v + final_b[0];
}

extern "C" void kernel_launch(void* const* d_in, const int* in_sizes, int n_in,
                              void* d_out, int out_size, void* d_ws, size_t ws_size,
                              hipStream_t stream) {
    const float* recent  = (const float*)d_in[0];
    const float* history = (const float*)d_in[1];
    const float* W_ih    = (const float*)d_in[2];
    const float* W_hh    = (const float*)d_in[3];
    const float* b_ih    = (const float*)d_in[4];
    const float* b_hh    = (const float*)d_in[5];
    const float* lin_W   = (const float*)d_in[6];
    const float* lin_b   = (const float*)d_in[7];
    const float* final_W = (const float*)d_in[8];
    const float* final_b = (const float*)d_in[9];
    float* out = (float*)d_out;
    float* per_mod = (float*)d_ws;

    if (ws_size >= WS_NEED) {
        __half*   w16   = (__half*)((char*)d_ws + WOFF_W16);
        float*    h_buf = (float*)((char*)d_ws + WOFF_H);
        unsigned* ctr   = (unsigned*)((char*)d_ws + WOFF_CTR);

        // zero per_mod + counters + h buffers each call (ws is not re-poisoned)
        hipMemsetAsync(d_ws, 0, WOFF_W16, stream);

        // convert W_hh to f16 (67.1M elems, 8 per thread)
        const int conv_blocks = (int)((size_t)NMOD * G4 * HID / 8 / 256);
        conv_kernel<<<conv_blocks, 256, 0, stream>>>(W_hh, w16);

        lstm_mb_kernel<<<NMOD * 4, 1024, 0, stream>>>(
            recent, history, W_ih, b_ih, b_hh, lin_W, lin_b,
            w16, h_buf, ctr, per_mod);
    } else {
        lstm_module_kernel<<<NMOD, 1024, 0, stream>>>(
            recent, history, W_ih, W_hh, b_ih, b_hh, lin_W, lin_b, per_mod);
    }
    finish_kernel<<<1, 64, 0, stream>>>(per_mod, final_W, final_b, out);
}

// Round 3
// 12360.381 us; speedup vs baseline: 3.7765x; 3.2284x over previous
//
#include <hip/hip_runtime.h>
#include <hip/hip_fp16.h>
#include <cstddef>

#define NMOD 64
#define HID 512
#define TSTEPS 1024
#define G4 2048           // gate rows per module

// ws layout
#define WOFF_PERMOD 0            // 64 f32
#define WOFF_CTR    1024         // 64 counters, stride 32 u32 (128B lines)
#define WOFF_H      16384        // 2 * 64 * 512 f32 = 256 KB
#define WOFF_W16    524288       // 64*2048*512 f16 = 128 MB
#define W16_BYTES   ((size_t)NMOD * G4 * HID * 2)
#define WS_NEED     (WOFF_W16 + W16_BYTES)

typedef _Float16 h2_t __attribute__((ext_vector_type(2)));
union U32H2 { unsigned u; h2_t h; };
__device__ __forceinline__ h2_t u2h(unsigned u) { U32H2 x; x.u = u; return x.h; }

#if __has_builtin(__builtin_amdgcn_fdot2)
#define FDOT2(a, b, c) __builtin_amdgcn_fdot2((a), (b), (c), false)
#else
__device__ __forceinline__ float FDOT2(h2_t a, h2_t b, float c) {
    return c + (float)a[0] * (float)b[0] + (float)a[1] * (float)b[1];
}
#endif

__device__ __forceinline__ float fsig(float x)  { return 1.0f / (1.0f + __expf(-x)); }
__device__ __forceinline__ float ftanh_(float x){ return 1.0f - 2.0f / (__expf(2.0f * x) + 1.0f); }

// ---------------- f32 -> f16 weight conversion (canonical [m][row][col]) ----
__global__ __launch_bounds__(256) void conv_kernel(const float* __restrict__ src,
                                                   __half* __restrict__ dst) {
    const size_t i = ((size_t)blockIdx.x * 256 + threadIdx.x) * 8;
    const float4 a = *reinterpret_cast<const float4*>(src + i);
    const float4 b = *reinterpret_cast<const float4*>(src + i + 4);
    __half2 h0 = __floats2half2_rn(a.x, a.y);
    __half2 h1 = __floats2half2_rn(a.z, a.w);
    __half2 h2 = __floats2half2_rn(b.x, b.y);
    __half2 h3 = __floats2half2_rn(b.z, b.w);
    uint4 o;
    o.x = *reinterpret_cast<unsigned*>(&h0);
    o.y = *reinterpret_cast<unsigned*>(&h1);
    o.z = *reinterpret_cast<unsigned*>(&h2);
    o.w = *reinterpret_cast<unsigned*>(&h3);
    *reinterpret_cast<uint4*>(dst + i) = o;
}

// ---------------- weights-resident LSTM: 4 blocks/module, 512 thr, 1 blk/CU --
// Thread (rg=tid>>4, cg=tid&15) owns local rows [rg*16, rg*16+16) x cols
// [cg*32, cg*32+32). Rows 0-11 in VGPRs, rows 12-15 in LDS (swizzled chunks).
// Butterfly reduce over cg lands local row rg*16+rev4(cg) on each thread.
__global__ __launch_bounds__(512, 2) void lstm_res_kernel(
    const float* __restrict__ recent,
    const float* __restrict__ history,
    const float* __restrict__ W_ih,
    const float* __restrict__ b_ih,
    const float* __restrict__ b_hh,
    const float* __restrict__ lin_W,
    const float* __restrict__ lin_b,
    const unsigned* __restrict__ w16u,  // f16 weights as u32 pairs
    float* h_buf_,                      // [2,64,512] f32, zeroed
    unsigned* ctr,                      // [64*32] u32, zeroed
    float* __restrict__ per_mod)        // [64]
{
    // XCD-grouping remap: module's 4 blocks land on one XCD (perf heuristic)
    const int bid = blockIdx.x;
    const int m = (bid & 7) * 8 + ((bid >> 3) >> 2);
    const int b = (bid >> 3) & 3;
    const int tid = threadIdx.x;
    const int rg = tid >> 4;   // 0..31
    const int cg = tid & 15;   // 0..15

    __shared__ unsigned w_lds[32768];   // 128 KB: [rg*4+r2][64 chunks][4 u32]
    __shared__ unsigned h_pk[256];      // full h as packed f16x2
    __shared__ float gates_sh[512];
    __shared__ float hist_sh[TSTEPS];
    __shared__ float red_sh[8];

    for (int i = tid; i < TSTEPS; i += 512)
        hist_sh[i] = history[(size_t)m * TSTEPS + i];

    // ---- load resident weights ----
    const size_t rowbase = (size_t)m * G4 * 256;   // u32 units, row stride 256
    uint4 w[12][4];
    #pragma unroll
    for (int r = 0; r < 12; ++r) {
        const int l = rg * 16 + r;
        const int gr = ((l >> 7) << 9) + (b << 7) + (l & 127);
        const uint4* src = (const uint4*)(w16u + rowbase + (size_t)gr * 256 + cg * 16);
        #pragma unroll
        for (int kk = 0; kk < 4; ++kk) w[r][kk] = src[kk];
    }
    #pragma unroll
    for (int r2 = 0; r2 < 4; ++r2) {
        const int l = rg * 16 + 12 + r2;
        const int gr = ((l >> 7) << 9) + (b << 7) + (l & 127);
        const uint4* src = (const uint4*)(w16u + rowbase + (size_t)gr * 256 + cg * 16);
        #pragma unroll
        for (int kk = 0; kk < 4; ++kk) {
            const int c = (cg * 4 + kk + rg) & 63;   // rotate-swizzle: conflict-free
            *(uint4*)&w_lds[((rg * 4 + r2) * 64 + c) * 4] = src[kk];
        }
    }

    // own output row (post-butterfly): l_own = rg*16 + rev4(cg)
    const int rev = ((cg & 1) << 3) | ((cg & 2) << 1) | ((cg & 4) >> 1) | ((cg & 8) >> 3);
    const int l_own = rg * 16 + rev;
    const int gr_own = ((l_own >> 7) << 9) + (b << 7) + (l_own & 127);
    const float wib_own  = W_ih[(size_t)m * G4 + gr_own];
    const float bias_own = b_ih[(size_t)m * G4 + gr_own] + b_hh[(size_t)m * G4 + gr_own];

    if (tid < 256) h_pk[tid] = 0u;
    float c_reg = 0.0f;   // lives in tid<128
    __syncthreads();

    volatile float* hbv = h_buf_;

    for (int t = 0; t < TSTEPS; ++t) {
        const float xv = hist_sh[t];
        float acc[16];
        #pragma unroll
        for (int r = 0; r < 16; ++r) acc[r] = 0.0f;

        #pragma unroll
        for (int kk = 0; kk < 4; ++kk) {
            const uint4 hq = *(const uint4*)&h_pk[(cg * 4 + kk) * 4];
            #pragma unroll
            for (int r = 0; r < 12; ++r) {
                acc[r] = FDOT2(u2h(w[r][kk].x), u2h(hq.x), acc[r]);
                acc[r] = FDOT2(u2h(w[r][kk].y), u2h(hq.y), acc[r]);
                acc[r] = FDOT2(u2h(w[r][kk].z), u2h(hq.z), acc[r]);
                acc[r] = FDOT2(u2h(w[r][kk].w), u2h(hq.w), acc[r]);
            }
            #pragma unroll
            for (int r2 = 0; r2 < 4; ++r2) {
                const int c = (cg * 4 + kk + rg) & 63;
                const uint4 lw = *(const uint4*)&w_lds[((rg * 4 + r2) * 64 + c) * 4];
                acc[12 + r2] = FDOT2(u2h(lw.x), u2h(hq.x), acc[12 + r2]);
                acc[12 + r2] = FDOT2(u2h(lw.y), u2h(hq.y), acc[12 + r2]);
                acc[12 + r2] = FDOT2(u2h(lw.z), u2h(hq.z), acc[12 + r2]);
                acc[12 + r2] = FDOT2(u2h(lw.w), u2h(hq.w), acc[12 + r2]);
            }
        }

        // payload-halving butterfly over cg bits (cols): 8+4+2+1 exchanges
        #pragma unroll
        for (int k = 0; k < 8; ++k) {
            const float send = (cg & 1) ? acc[k] : acc[8 + k];
            const float recv = __shfl_xor(send, 1, 64);
            acc[k] = ((cg & 1) ? acc[8 + k] : acc[k]) + recv;
        }
        #pragma unroll
        for (int k = 0; k < 4; ++k) {
            const float send = (cg & 2) ? acc[k] : acc[4 + k];
            const float recv = __shfl_xor(send, 2, 64);
            acc[k] = ((cg & 2) ? acc[4 + k] : acc[k]) + recv;
        }
        #pragma unroll
        for (int k = 0; k < 2; ++k) {
            const float send = (cg & 4) ? acc[k] : acc[2 + k];
            const float recv = __shfl_xor(send, 4, 64);
            acc[k] = ((cg & 4) ? acc[2 + k] : acc[k]) + recv;
        }
        {
            const float send = (cg & 8) ? acc[0] : acc[1];
            const float recv = __shfl_xor(send, 8, 64);
            acc[0] = ((cg & 8) ? acc[1] : acc[0]) + recv;
        }

        gates_sh[l_own] = acc[0] + xv * wib_own + bias_own;
        __syncthreads();

        if (tid < 128) {
            const float gi = fsig(gates_sh[tid]);
            const float gf = fsig(gates_sh[128 + tid]);
            const float gg = ftanh_(gates_sh[256 + tid]);
            const float go = fsig(gates_sh[384 + tid]);
            c_reg = gf * c_reg + gi * gg;
            const float hnew = go * ftanh_(c_reg);
            hbv[(size_t)((t + 1) & 1) * (NMOD * HID) + m * HID + b * 128 + tid] = hnew;
        }
        __syncthreads();   // drains vmcnt: h stores complete

        if (tid == 0) {
            __threadfence();
            __hip_atomic_fetch_add(&ctr[m * 32], 1u, __ATOMIC_RELEASE,
                                   __HIP_MEMORY_SCOPE_AGENT);
            const unsigned tgt = 4u * (unsigned)(t + 1);
            while (__hip_atomic_load(&ctr[m * 32], __ATOMIC_ACQUIRE,
                                     __HIP_MEMORY_SCOPE_AGENT) < tgt) {
                __builtin_amdgcn_s_sleep(1);
            }
            __threadfence();
        }
        __syncthreads();

        if (tid < 256) {
            const size_t base = (size_t)((t + 1) & 1) * (NMOD * HID) + m * HID;
            const float a  = hbv[base + 2 * tid];
            const float bb = hbv[base + 2 * tid + 1];
            __half2 hh = __floats2half2_rn(a, bb);
            h_pk[tid] = *reinterpret_cast<unsigned*>(&hh);
        }
        __syncthreads();
    }

    // per-module linear (block b==0); final h is in hb buffer 0 (1024 even)
    if (b == 0) {
        const float hv = hbv[(size_t)0 * (NMOD * HID) + m * HID + tid];
        float v = hv * lin_W[(size_t)m * (HID + 1) + tid];
        #pragma unroll
        for (int s2 = 32; s2; s2 >>= 1) v += __shfl_xor(v, s2, 64);
        if ((tid & 63) == 0) red_sh[tid >> 6] = v;
        __syncthreads();
        if (tid == 0) {
            float s = 0.0f;
            #pragma unroll
            for (int wv2 = 0; wv2 < 8; ++wv2) s += red_sh[wv2];
            s += recent[m] * lin_W[(size_t)m * (HID + 1) + HID] + lin_b[m];
            per_mod[m] = s;
        }
    }
}

// ---------------- fallback: round-1 f32 single-block-per-module kernel -------
__global__ __launch_bounds__(1024) void lstm_module_kernel(
    const float* __restrict__ recent,
    const float* __restrict__ history,
    const float* __restrict__ W_ih,
    const float* __restrict__ W_hh,
    const float* __restrict__ b_ih,
    const float* __restrict__ b_hh,
    const float* __restrict__ lin_W,
    const float* __restrict__ lin_b,
    float* __restrict__ per_mod)
{
    const int n = blockIdx.x;
    const int tid = threadIdx.x;

    __shared__ float h_sh[HID];
    __shared__ float gates_sh[G4];
    __shared__ float wib_sh[G4];
    __shared__ float bias_sh[G4];
    __shared__ float hist_sh[TSTEPS];

    for (int i = tid; i < G4; i += 1024) {
        wib_sh[i]  = W_ih[(size_t)n * G4 + i];
        bias_sh[i] = b_ih[(size_t)n * G4 + i] + b_hh[(size_t)n * G4 + i];
    }
    for (int i = tid; i < TSTEPS; i += 1024) hist_sh[i] = history[(size_t)n * TSTEPS + i];
    if (tid < HID) h_sh[tid] = 0.0f;
    float c_reg = 0.0f;
    __syncthreads();

    const int sub = tid & 15;
    const int rid = tid >> 4;
    const float* Wbase = W_hh + (size_t)n * G4 * HID;

    for (int t = 0; t < TSTEPS; ++t) {
        const float x = hist_sh[t];
        float hreg[32];
        #pragma unroll
        for (int j = 0; j < 8; ++j) {
            const float4 hv = *reinterpret_cast<const float4*>(&h_sh[sub * 4 + j * 64]);
            hreg[4 * j + 0] = hv.x; hreg[4 * j + 1] = hv.y;
            hreg[4 * j + 2] = hv.z; hreg[4 * j + 3] = hv.w;
        }
        for (int p = 0; p < 32; ++p) {
            const int r = p * 64 + rid;
            const float* wr = Wbase + (size_t)r * HID + sub * 4;
            float acc = 0.0f;
            #pragma unroll
            for (int j = 0; j < 8; ++j) {
                const float4 wv = *reinterpret_cast<const float4*>(wr + j * 64);
                acc += wv.x * hreg[4*j+0] + wv.y * hreg[4*j+1]
                     + wv.z * hreg[4*j+2] + wv.w * hreg[4*j+3];
            }
            acc += __shfl_xor(acc, 1, 64);
            acc += __shfl_xor(acc, 2, 64);
            acc += __shfl_xor(acc, 4, 64);
            acc += __shfl_xor(acc, 8, 64);
            if (sub == 0) gates_sh[r] = acc + x * wib_sh[r] + bias_sh[r];
        }
        __syncthreads();
        if (tid < HID) {
            const float ig = fsig(gates_sh[tid]);
            const float fg = fsig(gates_sh[HID + tid]);
            const float gg = ftanh_(gates_sh[2 * HID + tid]);
            const float og = fsig(gates_sh[3 * HID + tid]);
            c_reg = fg * c_reg + ig * gg;
            h_sh[tid] = og * ftanh_(c_reg);
        }
        __syncthreads();
    }

    if (tid < HID) {
        float v = h_sh[tid] * lin_W[(size_t)n * (HID + 1) + tid];
        #pragma unroll
        for (int m2 = 32; m2; m2 >>= 1) v += __shfl_xor(v, m2, 64);
        if ((tid & 63) == 0) gates_sh[tid >> 6] = v;
    }
    __syncthreads();
    if (tid == 0) {
        float s = 0.0f;
        #pragma unroll
        for (int w = 0; w < HID / 64; ++w) s += gates_sh[w];
        s += recent[n] * lin_W[(size_t)n * (HID + 1) + HID] + lin_b[n];
        per_mod[n] = s;
    }
}

__global__ void finish_kernel(const float* __restrict__ per_mod,
                              const float* __restrict__ final_W,
                              const float* __restrict__ final_b,
                              float* __restrict__ out)
{
    const int l = threadIdx.x;
    float v = per_mod[l] * final_W[l];
    #pragma unroll
    for (int m = 32; m; m >>= 1) v += __shfl_xor(v, m, 64);
    if (l == 0) out[0] = v + final_b[0];
}

extern "C" void kernel_launch(void* const* d_in, const int* in_sizes, int n_in,
                              void* d_out, int out_size, void* d_ws, size_t ws_size,
                              hipStream_t stream) {
    const float* recent  = (const float*)d_in[0];
    const float* history = (const float*)d_in[1];
    const float* W_ih    = (const float*)d_in[2];
    const float* W_hh    = (const float*)d_in[3];
    const float* b_ih    = (const float*)d_in[4];
    const float* b_hh    = (const float*)d_in[5];
    const float* lin_W   = (const float*)d_in[6];
    const float* lin_b   = (const float*)d_in[7];
    const float* final_W = (const float*)d_in[8];
    const float* final_b = (const float*)d_in[9];
    float* out = (float*)d_out;
    float* per_mod = (float*)d_ws;

    if (ws_size >= WS_NEED) {
        __half*   w16   = (__half*)((char*)d_ws + WOFF_W16);
        float*    h_buf = (float*)((char*)d_ws + WOFF_H);
        unsigned* ctr   = (unsigned*)((char*)d_ws + WOFF_CTR);

        hipMemsetAsync(d_ws, 0, WOFF_W16, stream);

        const int conv_blocks = (int)((size_t)NMOD * G4 * HID / 8 / 256);
        conv_kernel<<<conv_blocks, 256, 0, stream>>>(W_hh, w16);

        lstm_res_kernel<<<NMOD * 4, 512, 0, stream>>>(
            recent, history, W_ih, b_ih, b_hh, lin_W, lin_b,
            (const unsigned*)w16, h_buf, ctr, per_mod);
    } else {
        lstm_module_kernel<<<NMOD, 1024, 0, stream>>>(
            recent, history, W_ih, W_hh, b_ih, b_hh, lin_W, lin_b, per_mod);
    }
    finish_kernel<<<1, 64, 0, stream>>>(per_mod, final_W, final_b, out);
}

// Round 4
// 2652.662 us; speedup vs baseline: 17.5970x; 4.6596x over previous
//
#include <hip/hip_runtime.h>
#include <hip/hip_fp16.h>
#include <cstddef>

#define NMOD 64
#define HID 512
#define TSTEPS 1024
#define G4 2048           // gate rows per module

// ws layout
#define WOFF_PERMOD 0            // 64 f32
#define WOFF_HX     16384        // 2*64*256 u64 seq-tagged h pairs = 256 KB
#define WOFF_W16    524288       // 64*2048*512 f16 = 128 MB
#define W16_BYTES   ((size_t)NMOD * G4 * HID * 2)
#define WS_NEED     (WOFF_W16 + W16_BYTES)

typedef _Float16 h2_t __attribute__((ext_vector_type(2)));
union U32H2 { unsigned u; h2_t h; };
__device__ __forceinline__ h2_t u2h(unsigned u) { U32H2 x; x.u = u; return x.h; }

#if __has_builtin(__builtin_amdgcn_fdot2)
#define FDOT2(a, b, c) __builtin_amdgcn_fdot2((a), (b), (c), false)
#else
__device__ __forceinline__ float FDOT2(h2_t a, h2_t b, float c) {
    return c + (float)a[0] * (float)b[0] + (float)a[1] * (float)b[1];
}
#endif

__device__ __forceinline__ float fsig(float x)  { return 1.0f / (1.0f + __expf(-x)); }
__device__ __forceinline__ float ftanh_(float x){ return 1.0f - 2.0f / (__expf(2.0f * x) + 1.0f); }

// ---------------- f32 -> f16 weight conversion ------------------------------
__global__ __launch_bounds__(256) void conv_kernel(const float* __restrict__ src,
                                                   __half* __restrict__ dst) {
    const size_t i = ((size_t)blockIdx.x * 256 + threadIdx.x) * 8;
    const float4 a = *reinterpret_cast<const float4*>(src + i);
    const float4 b = *reinterpret_cast<const float4*>(src + i + 4);
    __half2 h0 = __floats2half2_rn(a.x, a.y);
    __half2 h1 = __floats2half2_rn(a.z, a.w);
    __half2 h2 = __floats2half2_rn(b.x, b.y);
    __half2 h3 = __floats2half2_rn(b.z, b.w);
    uint4 o;
    o.x = *reinterpret_cast<unsigned*>(&h0);
    o.y = *reinterpret_cast<unsigned*>(&h1);
    o.z = *reinterpret_cast<unsigned*>(&h2);
    o.w = *reinterpret_cast<unsigned*>(&h3);
    *reinterpret_cast<uint4*>(dst + i) = o;
}

// ---------------- weights-resident LSTM, fence-free seq-tagged exchange -----
// 4 blocks/module, 512 thr, 1 block/CU. Thread (rg,cg) owns local rows
// [rg*16,rg*16+16) x cols [cg*32,cg*32+32); rows 0-11 in VGPRs, 12-15 in LDS.
// Exchange: u64 word = (seq<<32)|f16x2 pair, relaxed agent atomics. Writers
// tid<64 (2 h elems each); readers tid 64..255 poll the 192 remote pairs.
// Max skew between blocks of a module is 1 step -> parity double-buffer safe.
__global__ __launch_bounds__(512, 2) void lstm_res_kernel(
    const float* __restrict__ recent,
    const float* __restrict__ history,
    const float* __restrict__ W_ih,
    const float* __restrict__ b_ih,
    const float* __restrict__ b_hh,
    const float* __restrict__ lin_W,
    const float* __restrict__ lin_b,
    const unsigned* __restrict__ w16u,  // f16 weights as u32 pairs
    unsigned long long* hx,             // [2][64][256] seq-tagged pairs, zeroed
    float* __restrict__ per_mod)        // [64]
{
    // XCD-grouping remap: module's 4 blocks land on one XCD under round-robin
    const int bid = blockIdx.x;
    const int m = (bid & 7) * 8 + ((bid >> 3) >> 2);
    const int b = (bid >> 3) & 3;
    const int tid = threadIdx.x;
    const int rg = tid >> 4;   // 0..31
    const int cg = tid & 15;   // 0..15

    __shared__ unsigned w_lds[32768];   // 128 KB: [rg*4+r2][64 chunks][4 u32]
    __shared__ unsigned h_pk[256];      // full h as packed f16x2
    __shared__ float gates_sh[512];
    __shared__ float hist_sh[TSTEPS];
    __shared__ float red_sh[8];

    for (int i = tid; i < TSTEPS; i += 512)
        hist_sh[i] = history[(size_t)m * TSTEPS + i];

    // ---- load resident weights ----
    const size_t rowbase = (size_t)m * G4 * 256;   // u32 units, row stride 256
    uint4 w[12][4];
    #pragma unroll
    for (int r = 0; r < 12; ++r) {
        const int l = rg * 16 + r;
        const int gr = ((l >> 7) << 9) + (b << 7) + (l & 127);
        const uint4* src = (const uint4*)(w16u + rowbase + (size_t)gr * 256 + cg * 16);
        #pragma unroll
        for (int kk = 0; kk < 4; ++kk) w[r][kk] = src[kk];
    }
    #pragma unroll
    for (int r2 = 0; r2 < 4; ++r2) {
        const int l = rg * 16 + 12 + r2;
        const int gr = ((l >> 7) << 9) + (b << 7) + (l & 127);
        const uint4* src = (const uint4*)(w16u + rowbase + (size_t)gr * 256 + cg * 16);
        #pragma unroll
        for (int kk = 0; kk < 4; ++kk) {
            const int c = (cg * 4 + kk + rg) & 63;   // rotate-swizzle
            *(uint4*)&w_lds[((rg * 4 + r2) * 64 + c) * 4] = src[kk];
        }
    }

    // own output row (post-butterfly): l_own = rg*16 + rev4(cg)
    const int rev = ((cg & 1) << 3) | ((cg & 2) << 1) | ((cg & 4) >> 1) | ((cg & 8) >> 3);
    const int l_own = rg * 16 + rev;
    const int gr_own = ((l_own >> 7) << 9) + (b << 7) + (l_own & 127);
    const float wib_own  = W_ih[(size_t)m * G4 + gr_own];
    const float bias_own = b_ih[(size_t)m * G4 + gr_own] + b_hh[(size_t)m * G4 + gr_own];

    if (tid < 256) h_pk[tid] = 0u;
    float c0 = 0.0f, c1 = 0.0f;   // cell state, lives in tid<64
    __syncthreads();

    for (int t = 0; t < TSTEPS; ++t) {
        const float xv = hist_sh[t];
        float acc[16];
        #pragma unroll
        for (int r = 0; r < 16; ++r) acc[r] = 0.0f;

        #pragma unroll
        for (int kk = 0; kk < 4; ++kk) {
            const uint4 hq = *(const uint4*)&h_pk[(cg * 4 + kk) * 4];
            #pragma unroll
            for (int r = 0; r < 12; ++r) {
                acc[r] = FDOT2(u2h(w[r][kk].x), u2h(hq.x), acc[r]);
                acc[r] = FDOT2(u2h(w[r][kk].y), u2h(hq.y), acc[r]);
                acc[r] = FDOT2(u2h(w[r][kk].z), u2h(hq.z), acc[r]);
                acc[r] = FDOT2(u2h(w[r][kk].w), u2h(hq.w), acc[r]);
            }
            #pragma unroll
            for (int r2 = 0; r2 < 4; ++r2) {
                const int c = (cg * 4 + kk + rg) & 63;
                const uint4 lw = *(const uint4*)&w_lds[((rg * 4 + r2) * 64 + c) * 4];
                acc[12 + r2] = FDOT2(u2h(lw.x), u2h(hq.x), acc[12 + r2]);
                acc[12 + r2] = FDOT2(u2h(lw.y), u2h(hq.y), acc[12 + r2]);
                acc[12 + r2] = FDOT2(u2h(lw.z), u2h(hq.z), acc[12 + r2]);
                acc[12 + r2] = FDOT2(u2h(lw.w), u2h(hq.w), acc[12 + r2]);
            }
        }

        // payload-halving butterfly over cg bits: 8+4+2+1 exchanges
        #pragma unroll
        for (int k = 0; k < 8; ++k) {
            const float send = (cg & 1) ? acc[k] : acc[8 + k];
            const float recv = __shfl_xor(send, 1, 64);
            acc[k] = ((cg & 1) ? acc[8 + k] : acc[k]) + recv;
        }
        #pragma unroll
        for (int k = 0; k < 4; ++k) {
            const float send = (cg & 2) ? acc[k] : acc[4 + k];
            const float recv = __shfl_xor(send, 2, 64);
            acc[k] = ((cg & 2) ? acc[4 + k] : acc[k]) + recv;
        }
        #pragma unroll
        for (int k = 0; k < 2; ++k) {
            const float send = (cg & 4) ? acc[k] : acc[2 + k];
            const float recv = __shfl_xor(send, 4, 64);
            acc[k] = ((cg & 4) ? acc[2 + k] : acc[k]) + recv;
        }
        {
            const float send = (cg & 8) ? acc[0] : acc[1];
            const float recv = __shfl_xor(send, 8, 64);
            acc[0] = ((cg & 8) ? acc[1] : acc[0]) + recv;
        }

        gates_sh[l_own] = acc[0] + xv * wib_own + bias_own;
        __syncthreads();

        const unsigned seq = (unsigned)(t + 1);
        const size_t pbase = (size_t)(seq & 1) * (NMOD * 256) + (size_t)m * 256;

        if (tid < 64) {
            // cell update for elements 2*tid, 2*tid+1 of my 128-segment
            const int e0 = 2 * tid, e1 = 2 * tid + 1;
            const float gi0 = fsig(gates_sh[e0]);
            const float gf0 = fsig(gates_sh[128 + e0]);
            const float gg0 = ftanh_(gates_sh[256 + e0]);
            const float go0 = fsig(gates_sh[384 + e0]);
            c0 = gf0 * c0 + gi0 * gg0;
            const float h0 = go0 * ftanh_(c0);
            const float gi1 = fsig(gates_sh[e1]);
            const float gf1 = fsig(gates_sh[128 + e1]);
            const float gg1 = ftanh_(gates_sh[256 + e1]);
            const float go1 = fsig(gates_sh[384 + e1]);
            c1 = gf1 * c1 + gi1 * gg1;
            const float h1 = go1 * ftanh_(c1);
            __half2 hh = __floats2half2_rn(h0, h1);
            const unsigned pay = *reinterpret_cast<unsigned*>(&hh);
            const unsigned long long v = ((unsigned long long)seq << 32) | pay;
            __hip_atomic_store(&hx[pbase + b * 64 + tid], v,
                               __ATOMIC_RELAXED, __HIP_MEMORY_SCOPE_AGENT);
            h_pk[b * 64 + tid] = pay;   // local pairs skip memory
        } else if (tid < 256) {
            // poll one remote pair until its seq matches
            const int p_idx = (b * 64 + tid) & 255;   // (b*64 + 64 + (tid-64)) mod 256
            const unsigned long long* ap = &hx[pbase + p_idx];
            unsigned long long v;
            do {
                v = __hip_atomic_load(ap, __ATOMIC_RELAXED, __HIP_MEMORY_SCOPE_AGENT);
            } while ((unsigned)(v >> 32) != seq);
            h_pk[p_idx] = (unsigned)v;
        }
        __syncthreads();
    }

    // per-module linear from f16 h (block b==0)
    if (b == 0) {
        float v = 0.0f;
        if (tid < 256) {
            U32H2 u; u.u = h_pk[tid];
            const float* lwp = lin_W + (size_t)m * (HID + 1);
            v = (float)u.h[0] * lwp[2 * tid] + (float)u.h[1] * lwp[2 * tid + 1];
        }
        #pragma unroll
        for (int s2 = 32; s2; s2 >>= 1) v += __shfl_xor(v, s2, 64);
        if ((tid & 63) == 0) red_sh[tid >> 6] = v;
        __syncthreads();
        if (tid == 0) {
            float s = 0.0f;
            #pragma unroll
            for (int wv2 = 0; wv2 < 8; ++wv2) s += red_sh[wv2];
            s += recent[m] * lin_W[(size_t)m * (HID + 1) + HID] + lin_b[m];
            per_mod[m] = s;
        }
    }
}

// ---------------- fallback: round-1 f32 single-block-per-module kernel -------
__global__ __launch_bounds__(1024) void lstm_module_kernel(
    const float* __restrict__ recent,
    const float* __restrict__ history,
    const float* __restrict__ W_ih,
    const float* __restrict__ W_hh,
    const float* __restrict__ b_ih,
    const float* __restrict__ b_hh,
    const float* __restrict__ lin_W,
    const float* __restrict__ lin_b,
    float* __restrict__ per_mod)
{
    const int n = blockIdx.x;
    const int tid = threadIdx.x;

    __shared__ float h_sh[HID];
    __shared__ float gates_sh[G4];
    __shared__ float wib_sh[G4];
    __shared__ float bias_sh[G4];
    __shared__ float hist_sh[TSTEPS];

    for (int i = tid; i < G4; i += 1024) {
        wib_sh[i]  = W_ih[(size_t)n * G4 + i];
        bias_sh[i] = b_ih[(size_t)n * G4 + i] + b_hh[(size_t)n * G4 + i];
    }
    for (int i = tid; i < TSTEPS; i += 1024) hist_sh[i] = history[(size_t)n * TSTEPS + i];
    if (tid < HID) h_sh[tid] = 0.0f;
    float c_reg = 0.0f;
    __syncthreads();

    const int sub = tid & 15;
    const int rid = tid >> 4;
    const float* Wbase = W_hh + (size_t)n * G4 * HID;

    for (int t = 0; t < TSTEPS; ++t) {
        const float x = hist_sh[t];
        float hreg[32];
        #pragma unroll
        for (int j = 0; j < 8; ++j) {
            const float4 hv = *reinterpret_cast<const float4*>(&h_sh[sub * 4 + j * 64]);
            hreg[4 * j + 0] = hv.x; hreg[4 * j + 1] = hv.y;
            hreg[4 * j + 2] = hv.z; hreg[4 * j + 3] = hv.w;
        }
        for (int p = 0; p < 32; ++p) {
            const int r = p * 64 + rid;
            const float* wr = Wbase + (size_t)r * HID + sub * 4;
            float acc = 0.0f;
            #pragma unroll
            for (int j = 0; j < 8; ++j) {
                const float4 wv = *reinterpret_cast<const float4*>(wr + j * 64);
                acc += wv.x * hreg[4*j+0] + wv.y * hreg[4*j+1]
                     + wv.z * hreg[4*j+2] + wv.w * hreg[4*j+3];
            }
            acc += __shfl_xor(acc, 1, 64);
            acc += __shfl_xor(acc, 2, 64);
            acc += __shfl_xor(acc, 4, 64);
            acc += __shfl_xor(acc, 8, 64);
            if (sub == 0) gates_sh[r] = acc + x * wib_sh[r] + bias_sh[r];
        }
        __syncthreads();
        if (tid < HID) {
            const float ig = fsig(gates_sh[tid]);
            const float fg = fsig(gates_sh[HID + tid]);
            const float gg = ftanh_(gates_sh[2 * HID + tid]);
            const float og = fsig(gates_sh[3 * HID + tid]);
            c_reg = fg * c_reg + ig * gg;
            h_sh[tid] = og * ftanh_(c_reg);
        }
        __syncthreads();
    }

    if (tid < HID) {
        float v = h_sh[tid] * lin_W[(size_t)n * (HID + 1) + tid];
        #pragma unroll
        for (int m2 = 32; m2; m2 >>= 1) v += __shfl_xor(v, m2, 64);
        if ((tid & 63) == 0) gates_sh[tid >> 6] = v;
    }
    __syncthreads();
    if (tid == 0) {
        float s = 0.0f;
        #pragma unroll
        for (int w = 0; w < HID / 64; ++w) s += gates_sh[w];
        s += recent[n] * lin_W[(size_t)n * (HID + 1) + HID] + lin_b[n];
        per_mod[n] = s;
    }
}

__global__ void finish_kernel(const float* __restrict__ per_mod,
                              const float* __restrict__ final_W,
                              const float* __restrict__ final_b,
                              float* __restrict__ out)
{
    const int l = threadIdx.x;
    float v = per_mod[l] * final_W[l];
    #pragma unroll
    for (int m = 32; m; m >>= 1) v += __shfl_xor(v, m, 64);
    if (l == 0) out[0] = v + final_b[0];
}

extern "C" void kernel_launch(void* const* d_in, const int* in_sizes, int n_in,
                              void* d_out, int out_size, void* d_ws, size_t ws_size,
                              hipStream_t stream) {
    const float* recent  = (const float*)d_in[0];
    const float* history = (const float*)d_in[1];
    const float* W_ih    = (const float*)d_in[2];
    const float* W_hh    = (const float*)d_in[3];
    const float* b_ih    = (const float*)d_in[4];
    const float* b_hh    = (const float*)d_in[5];
    const float* lin_W   = (const float*)d_in[6];
    const float* lin_b   = (const float*)d_in[7];
    const float* final_W = (const float*)d_in[8];
    const float* final_b = (const float*)d_in[9];
    float* out = (float*)d_out;
    float* per_mod = (float*)d_ws;

    if (ws_size >= WS_NEED) {
        __half* w16 = (__half*)((char*)d_ws + WOFF_W16);
        unsigned long long* hx = (unsigned long long*)((char*)d_ws + WOFF_HX);

        // zero per_mod + hx each call (ws is not re-poisoned between replays)
        hipMemsetAsync(d_ws, 0, WOFF_W16, stream);

        const int conv_blocks = (int)((size_t)NMOD * G4 * HID / 8 / 256);
        conv_kernel<<<conv_blocks, 256, 0, stream>>>(W_hh, w16);

        lstm_res_kernel<<<NMOD * 4, 512, 0, stream>>>(
            recent, history, W_ih, b_ih, b_hh, lin_W, lin_b,
            (const unsigned*)w16, hx, per_mod);
    } else {
        lstm_module_kernel<<<NMOD, 1024, 0, stream>>>(
            recent, history, W_ih, W_hh, b_ih, b_hh, lin_W, lin_b, per_mod);
    }
    finish_kernel<<<1, 64, 0, stream>>>(per_mod, final_W, final_b, out);
}

// Round 5
// 2586.612 us; speedup vs baseline: 18.0463x; 1.0255x over previous
//
#include <hip/hip_runtime.h>
#include <hip/hip_fp16.h>
#include <cstddef>

#define NMOD 64
#define HID 512
#define TSTEPS 1024
#define G4 2048           // gate rows per module

// ws layout
#define WOFF_PERMOD 0            // 64 f32
#define WOFF_HX     16384        // 2*64*256 u64 seq-tagged h pairs = 256 KB
#define WOFF_W16    524288       // 64*2048*512 f16 = 128 MB
#define W16_BYTES   ((size_t)NMOD * G4 * HID * 2)
#define WS_NEED     (WOFF_W16 + W16_BYTES)

typedef _Float16 h2_t __attribute__((ext_vector_type(2)));
union U32H2 { unsigned u; h2_t h; };
__device__ __forceinline__ h2_t u2h(unsigned u) { U32H2 x; x.u = u; return x.h; }

#if __has_builtin(__builtin_amdgcn_fdot2)
#define FDOT2(a, b, c) __builtin_amdgcn_fdot2((a), (b), (c), false)
#else
__device__ __forceinline__ float FDOT2(h2_t a, h2_t b, float c) {
    return c + (float)a[0] * (float)b[0] + (float)a[1] * (float)b[1];
}
#endif

__device__ __forceinline__ float fsig(float x)  { return 1.0f / (1.0f + __expf(-x)); }
__device__ __forceinline__ float ftanh_(float x){ return 1.0f - 2.0f / (__expf(2.0f * x) + 1.0f); }

// ---------------- f32 -> f16 weight conversion ------------------------------
__global__ __launch_bounds__(256) void conv_kernel(const float* __restrict__ src,
                                                   __half* __restrict__ dst) {
    const size_t i = ((size_t)blockIdx.x * 256 + threadIdx.x) * 8;
    const float4 a = *reinterpret_cast<const float4*>(src + i);
    const float4 b = *reinterpret_cast<const float4*>(src + i + 4);
    __half2 h0 = __floats2half2_rn(a.x, a.y);
    __half2 h1 = __floats2half2_rn(a.z, a.w);
    __half2 h2 = __floats2half2_rn(b.x, b.y);
    __half2 h3 = __floats2half2_rn(b.z, b.w);
    uint4 o;
    o.x = *reinterpret_cast<unsigned*>(&h0);
    o.y = *reinterpret_cast<unsigned*>(&h1);
    o.z = *reinterpret_cast<unsigned*>(&h2);
    o.w = *reinterpret_cast<unsigned*>(&h3);
    *reinterpret_cast<uint4*>(dst + i) = o;
}

// ---------------- weights-resident LSTM, region-interleaved chunks ----------
// 4 blocks/module, 512 thr, 1 block/CU. Thread (rg=tid>>4, cg=tid&15) owns
// 16 local rows; its kk-th 8-col chunk comes from h REGION (b+kk)&3 at
// position cg (kk=0 == local region -> computable before remote h arrives).
// h_pk linear [256] u32 pairs; chunk reads are consecutive across cg (2-way,
// free). LDS rows 12-15 use wc=((kk+rg)&3)*16+cg (conflict-free per 16-lane
// group). Exchange: u64 = (seq<<32)|f16x2, relaxed agent atomics, parity
// double-buffer (max skew 1 step, proven transitively).
__global__ __launch_bounds__(512, 2) void lstm_res_kernel(
    const float* __restrict__ recent,
    const float* __restrict__ history,
    const float* __restrict__ W_ih,
    const float* __restrict__ b_ih,
    const float* __restrict__ b_hh,
    const float* __restrict__ lin_W,
    const float* __restrict__ lin_b,
    const unsigned* __restrict__ w16u,  // f16 weights as u32 pairs
    unsigned long long* hx,             // [2][64][256] seq-tagged pairs, zeroed
    float* __restrict__ per_mod)        // [64]
{
    // XCD-grouping remap: module's 4 blocks land on one XCD under round-robin
    const int bid = blockIdx.x;
    const int m = (bid & 7) * 8 + ((bid >> 3) >> 2);
    const int b = (bid >> 3) & 3;
    const int tid = threadIdx.x;
    const int rg = tid >> 4;   // 0..31
    const int cg = tid & 15;   // 0..15

    __shared__ unsigned w_lds[32768];   // 128 KB: [row 0..127][64 chunks][4 u32]
    __shared__ unsigned h_pk[256];      // full h as packed f16x2, linear pairs
    __shared__ float gates_sh[512];
    __shared__ float hist_sh[TSTEPS];
    __shared__ float red_sh[8];

    for (int i = tid; i < TSTEPS; i += 512)
        hist_sh[i] = history[(size_t)m * TSTEPS + i];

    // ---- load resident weights (region-interleaved chunk mapping) ----
    const size_t rowbase = (size_t)m * G4 * 256;   // u32 units, row stride 256
    uint4 w[12][4];
    #pragma unroll
    for (int r = 0; r < 12; ++r) {
        const int l = rg * 16 + r;
        const int gr = ((l >> 7) << 9) + (b << 7) + (l & 127);
        #pragma unroll
        for (int kk = 0; kk < 4; ++kk) {
            const int c = (((b + kk) & 3) << 4) + cg;   // h chunk index
            w[r][kk] = *(const uint4*)(w16u + rowbase + (size_t)gr * 256 + c * 4);
        }
    }
    #pragma unroll
    for (int r2 = 0; r2 < 4; ++r2) {
        const int l = rg * 16 + 12 + r2;
        const int gr = ((l >> 7) << 9) + (b << 7) + (l & 127);
        #pragma unroll
        for (int kk = 0; kk < 4; ++kk) {
            const int c  = (((b + kk) & 3) << 4) + cg;
            const int wc = (((kk + rg) & 3) << 4) + cg;  // bank-spread position
            *(uint4*)&w_lds[((rg * 4 + r2) * 64 + wc) * 4] =
                *(const uint4*)(w16u + rowbase + (size_t)gr * 256 + c * 4);
        }
    }

    // own output row (post-butterfly): l_own = rg*16 + rev4(cg)
    const int rev = ((cg & 1) << 3) | ((cg & 2) << 1) | ((cg & 4) >> 1) | ((cg & 8) >> 3);
    const int l_own = rg * 16 + rev;
    const int gr_own = ((l_own >> 7) << 9) + (b << 7) + (l_own & 127);
    const float wib_own  = W_ih[(size_t)m * G4 + gr_own];
    const float bias_own = b_ih[(size_t)m * G4 + gr_own] + b_hh[(size_t)m * G4 + gr_own];

    // reader role: tid 64..255 each owns one remote word
    const bool is_writer = (tid < 64);
    const bool is_reader = (tid >= 64 && tid < 256);
    const int  rr    = tid - 64;                     // 0..191
    const int  widx  = (((b + 1 + (rr >> 6)) & 3) << 6) + (rr & 63);  // pair idx

    float c0 = 0.0f, c1 = 0.0f;   // cell state, lives in tid<64

    // prologue: h(0-context)=0 -> gates(t=0) are bias-only
    gates_sh[l_own] = hist_sh[0] * wib_own + bias_own;

    for (int t = 0; t < TSTEPS - 1; ++t) {
        __syncthreads();   // gates_sh(t) ready
        const unsigned seq = (unsigned)(t + 1);
        const size_t pbase = (size_t)(seq & 1) * (NMOD * 256) + (size_t)m * 256;

        unsigned long long pv = 0;
        if (is_writer) {
            // cell update for h elems 2*tid, 2*tid+1 of my 128-segment
            const int e0 = 2 * tid, e1 = 2 * tid + 1;
            const float gi0 = fsig(gates_sh[e0]);
            const float gf0 = fsig(gates_sh[128 + e0]);
            const float gg0 = ftanh_(gates_sh[256 + e0]);
            const float go0 = fsig(gates_sh[384 + e0]);
            c0 = gf0 * c0 + gi0 * gg0;
            const float h0 = go0 * ftanh_(c0);
            const float gi1 = fsig(gates_sh[e1]);
            const float gf1 = fsig(gates_sh[128 + e1]);
            const float gg1 = ftanh_(gates_sh[256 + e1]);
            const float go1 = fsig(gates_sh[384 + e1]);
            c1 = gf1 * c1 + gi1 * gg1;
            const float h1 = go1 * ftanh_(c1);
            __half2 hh = __floats2half2_rn(h0, h1);
            const unsigned pay = *reinterpret_cast<unsigned*>(&hh);
            __hip_atomic_store(&hx[pbase + b * 64 + tid],
                               ((unsigned long long)seq << 32) | pay,
                               __ATOMIC_RELAXED, __HIP_MEMORY_SCOPE_AGENT);
            h_pk[b * 64 + tid] = pay;   // local pairs skip memory
        } else if (is_reader) {
            // speculative first poll, overlapped with writers' cell phase
            pv = __hip_atomic_load(&hx[pbase + widx],
                                   __ATOMIC_RELAXED, __HIP_MEMORY_SCOPE_AGENT);
        }
        __syncthreads();   // local h_pk region valid

        // ---- kk=0: dots over LOCAL h region while remote h is in flight ----
        float acc[16];
        #pragma unroll
        for (int r = 0; r < 16; ++r) acc[r] = 0.0f;
        {
            const uint4 hq = *(const uint4*)&h_pk[(b << 6) + cg * 4];
            #pragma unroll
            for (int r = 0; r < 12; ++r) {
                acc[r] = FDOT2(u2h(w[r][0].x), u2h(hq.x), acc[r]);
                acc[r] = FDOT2(u2h(w[r][0].y), u2h(hq.y), acc[r]);
                acc[r] = FDOT2(u2h(w[r][0].z), u2h(hq.z), acc[r]);
                acc[r] = FDOT2(u2h(w[r][0].w), u2h(hq.w), acc[r]);
            }
            const int wc0 = ((rg & 3) << 4) + cg;
            #pragma unroll
            for (int r2 = 0; r2 < 4; ++r2) {
                const uint4 lw = *(const uint4*)&w_lds[((rg * 4 + r2) * 64 + wc0) * 4];
                acc[12 + r2] = FDOT2(u2h(lw.x), u2h(hq.x), acc[12 + r2]);
                acc[12 + r2] = FDOT2(u2h(lw.y), u2h(hq.y), acc[12 + r2]);
                acc[12 + r2] = FDOT2(u2h(lw.z), u2h(hq.z), acc[12 + r2]);
                acc[12 + r2] = FDOT2(u2h(lw.w), u2h(hq.w), acc[12 + r2]);
            }
        }

        if (is_reader) {
            while ((unsigned)(pv >> 32) != seq)
                pv = __hip_atomic_load(&hx[pbase + widx],
                                       __ATOMIC_RELAXED, __HIP_MEMORY_SCOPE_AGENT);
            h_pk[widx] = (unsigned)pv;
        }
        __syncthreads();   // full h_pk valid

        // ---- kk=1..3: remote-region dots ----
        #pragma unroll
        for (int kk = 1; kk < 4; ++kk) {
            const uint4 hq = *(const uint4*)&h_pk[((((b + kk) & 3)) << 6) + cg * 4];
            #pragma unroll
            for (int r = 0; r < 12; ++r) {
                acc[r] = FDOT2(u2h(w[r][kk].x), u2h(hq.x), acc[r]);
                acc[r] = FDOT2(u2h(w[r][kk].y), u2h(hq.y), acc[r]);
                acc[r] = FDOT2(u2h(w[r][kk].z), u2h(hq.z), acc[r]);
                acc[r] = FDOT2(u2h(w[r][kk].w), u2h(hq.w), acc[r]);
            }
            const int wc = (((kk + rg) & 3) << 4) + cg;
            #pragma unroll
            for (int r2 = 0; r2 < 4; ++r2) {
                const uint4 lw = *(const uint4*)&w_lds[((rg * 4 + r2) * 64 + wc) * 4];
                acc[12 + r2] = FDOT2(u2h(lw.x), u2h(hq.x), acc[12 + r2]);
                acc[12 + r2] = FDOT2(u2h(lw.y), u2h(hq.y), acc[12 + r2]);
                acc[12 + r2] = FDOT2(u2h(lw.z), u2h(hq.z), acc[12 + r2]);
                acc[12 + r2] = FDOT2(u2h(lw.w), u2h(hq.w), acc[12 + r2]);
            }
        }

        // payload-halving butterfly over cg bits: 8+4+2+1 exchanges
        #pragma unroll
        for (int k = 0; k < 8; ++k) {
            const float send = (cg & 1) ? acc[k] : acc[8 + k];
            const float recv = __shfl_xor(send, 1, 64);
            acc[k] = ((cg & 1) ? acc[8 + k] : acc[k]) + recv;
        }
        #pragma unroll
        for (int k = 0; k < 4; ++k) {
            const float send = (cg & 2) ? acc[k] : acc[4 + k];
            const float recv = __shfl_xor(send, 2, 64);
            acc[k] = ((cg & 2) ? acc[4 + k] : acc[k]) + recv;
        }
        #pragma unroll
        for (int k = 0; k < 2; ++k) {
            const float send = (cg & 4) ? acc[k] : acc[2 + k];
            const float recv = __shfl_xor(send, 4, 64);
            acc[k] = ((cg & 4) ? acc[2 + k] : acc[k]) + recv;
        }
        {
            const float send = (cg & 8) ? acc[0] : acc[1];
            const float recv = __shfl_xor(send, 8, 64);
            acc[0] = ((cg & 8) ? acc[1] : acc[0]) + recv;
        }

        gates_sh[l_own] = acc[0] + hist_sh[t + 1] * wib_own + bias_own;
    }

    // ---- epilogue: final cell update (t = TSTEPS-1) + one exchange ----
    __syncthreads();   // gates_sh(T-1) ready
    {
        const unsigned seq = (unsigned)TSTEPS;
        const size_t pbase = (size_t)(seq & 1) * (NMOD * 256) + (size_t)m * 256;
        if (is_writer) {
            const int e0 = 2 * tid, e1 = 2 * tid + 1;
            const float gi0 = fsig(gates_sh[e0]);
            const float gf0 = fsig(gates_sh[128 + e0]);
            const float gg0 = ftanh_(gates_sh[256 + e0]);
            const float go0 = fsig(gates_sh[384 + e0]);
            c0 = gf0 * c0 + gi0 * gg0;
            const float h0 = go0 * ftanh_(c0);
            const float gi1 = fsig(gates_sh[e1]);
            const float gf1 = fsig(gates_sh[128 + e1]);
            const float gg1 = ftanh_(gates_sh[256 + e1]);
            const float go1 = fsig(gates_sh[384 + e1]);
            c1 = gf1 * c1 + gi1 * gg1;
            const float h1 = go1 * ftanh_(c1);
            __half2 hh = __floats2half2_rn(h0, h1);
            const unsigned pay = *reinterpret_cast<unsigned*>(&hh);
            __hip_atomic_store(&hx[pbase + b * 64 + tid],
                               ((unsigned long long)seq << 32) | pay,
                               __ATOMIC_RELAXED, __HIP_MEMORY_SCOPE_AGENT);
            h_pk[b * 64 + tid] = pay;
        }
        if (b == 0) {
            if (is_reader) {
                unsigned long long pv;
                do {
                    pv = __hip_atomic_load(&hx[pbase + widx],
                                           __ATOMIC_RELAXED, __HIP_MEMORY_SCOPE_AGENT);
                } while ((unsigned)(pv >> 32) != seq);
                h_pk[widx] = (unsigned)pv;
            }
            __syncthreads();
            // per-module linear from f16 h
            float v = 0.0f;
            if (tid < 256) {
                U32H2 u; u.u = h_pk[tid];
                const float* lwp = lin_W + (size_t)m * (HID + 1);
                v = (float)u.h[0] * lwp[2 * tid] + (float)u.h[1] * lwp[2 * tid + 1];
            }
            #pragma unroll
            for (int s2 = 32; s2; s2 >>= 1) v += __shfl_xor(v, s2, 64);
            if ((tid & 63) == 0) red_sh[tid >> 6] = v;
            __syncthreads();
            if (tid == 0) {
                float s = 0.0f;
                #pragma unroll
                for (int wv2 = 0; wv2 < 8; ++wv2) s += red_sh[wv2];
                s += recent[m] * lin_W[(size_t)m * (HID + 1) + HID] + lin_b[m];
                per_mod[m] = s;
            }
        }
    }
}

// ---------------- fallback: round-1 f32 single-block-per-module kernel -------
__global__ __launch_bounds__(1024) void lstm_module_kernel(
    const float* __restrict__ recent,
    const float* __restrict__ history,
    const float* __restrict__ W_ih,
    const float* __restrict__ W_hh,
    const float* __restrict__ b_ih,
    const float* __restrict__ b_hh,
    const float* __restrict__ lin_W,
    const float* __restrict__ lin_b,
    float* __restrict__ per_mod)
{
    const int n = blockIdx.x;
    const int tid = threadIdx.x;

    __shared__ float h_sh[HID];
    __shared__ float gates_sh[G4];
    __shared__ float wib_sh[G4];
    __shared__ float bias_sh[G4];
    __shared__ float hist_sh[TSTEPS];

    for (int i = tid; i < G4; i += 1024) {
        wib_sh[i]  = W_ih[(size_t)n * G4 + i];
        bias_sh[i] = b_ih[(size_t)n * G4 + i] + b_hh[(size_t)n * G4 + i];
    }
    for (int i = tid; i < TSTEPS; i += 1024) hist_sh[i] = history[(size_t)n * TSTEPS + i];
    if (tid < HID) h_sh[tid] = 0.0f;
    float c_reg = 0.0f;
    __syncthreads();

    const int sub = tid & 15;
    const int rid = tid >> 4;
    const float* Wbase = W_hh + (size_t)n * G4 * HID;

    for (int t = 0; t < TSTEPS; ++t) {
        const float x = hist_sh[t];
        float hreg[32];
        #pragma unroll
        for (int j = 0; j < 8; ++j) {
            const float4 hv = *reinterpret_cast<const float4*>(&h_sh[sub * 4 + j * 64]);
            hreg[4 * j + 0] = hv.x; hreg[4 * j + 1] = hv.y;
            hreg[4 * j + 2] = hv.z; hreg[4 * j + 3] = hv.w;
        }
        for (int p = 0; p < 32; ++p) {
            const int r = p * 64 + rid;
            const float* wr = Wbase + (size_t)r * HID + sub * 4;
            float acc = 0.0f;
            #pragma unroll
            for (int j = 0; j < 8; ++j) {
                const float4 wv = *reinterpret_cast<const float4*>(wr + j * 64);
                acc += wv.x * hreg[4*j+0] + wv.y * hreg[4*j+1]
                     + wv.z * hreg[4*j+2] + wv.w * hreg[4*j+3];
            }
            acc += __shfl_xor(acc, 1, 64);
            acc += __shfl_xor(acc, 2, 64);
            acc += __shfl_xor(acc, 4, 64);
            acc += __shfl_xor(acc, 8, 64);
            if (sub == 0) gates_sh[r] = acc + x * wib_sh[r] + bias_sh[r];
        }
        __syncthreads();
        if (tid < HID) {
            const float ig = fsig(gates_sh[tid]);
            const float fg = fsig(gates_sh[HID + tid]);
            const float gg = ftanh_(gates_sh[2 * HID + tid]);
            const float og = fsig(gates_sh[3 * HID + tid]);
            c_reg = fg * c_reg + ig * gg;
            h_sh[tid] = og * ftanh_(c_reg);
        }
        __syncthreads();
    }

    if (tid < HID) {
        float v = h_sh[tid] * lin_W[(size_t)n * (HID + 1) + tid];
        #pragma unroll
        for (int m2 = 32; m2; m2 >>= 1) v += __shfl_xor(v, m2, 64);
        if ((tid & 63) == 0) gates_sh[tid >> 6] = v;
    }
    __syncthreads();
    if (tid == 0) {
        float s = 0.0f;
        #pragma unroll
        for (int w = 0; w < HID / 64; ++w) s += gates_sh[w];
        s += recent[n] * lin_W[(size_t)n * (HID + 1) + HID] + lin_b[n];
        per_mod[n] = s;
    }
}

__global__ void finish_kernel(const float* __restrict__ per_mod,
                              const float* __restrict__ final_W,
                              const float* __restrict__ final_b,
                              float* __restrict__ out)
{
    const int l = threadIdx.x;
    float v = per_mod[l] * final_W[l];
    #pragma unroll
    for (int m = 32; m; m >>= 1) v += __shfl_xor(v, m, 64);
    if (l == 0) out[0] = v + final_b[0];
}

extern "C" void kernel_launch(void* const* d_in, const int* in_sizes, int n_in,
                              void* d_out, int out_size, void* d_ws, size_t ws_size,
                              hipStream_t stream) {
    const float* recent  = (const float*)d_in[0];
    const float* history = (const float*)d_in[1];
    const float* W_ih    = (const float*)d_in[2];
    const float* W_hh    = (const float*)d_in[3];
    const float* b_ih    = (const float*)d_in[4];
    const float* b_hh    = (const float*)d_in[5];
    const float* lin_W   = (const float*)d_in[6];
    const float* lin_b   = (const float*)d_in[7];
    const float* final_W = (const float*)d_in[8];
    const float* final_b = (const float*)d_in[9];
    float* out = (float*)d_out;
    float* per_mod = (float*)d_ws;

    if (ws_size >= WS_NEED) {
        __half* w16 = (__half*)((char*)d_ws + WOFF_W16);
        unsigned long long* hx = (unsigned long long*)((char*)d_ws + WOFF_HX);

        // zero per_mod + hx each call (ws is not re-poisoned between replays)
        hipMemsetAsync(d_ws, 0, WOFF_W16, stream);

        const int conv_blocks = (int)((size_t)NMOD * G4 * HID / 8 / 256);
        conv_kernel<<<conv_blocks, 256, 0, stream>>>(W_hh, w16);

        lstm_res_kernel<<<NMOD * 4, 512, 0, stream>>>(
            recent, history, W_ih, b_ih, b_hh, lin_W, lin_b,
            (const unsigned*)w16, hx, per_mod);
    } else {
        lstm_module_kernel<<<NMOD, 1024, 0, stream>>>(
            recent, history, W_ih, W_hh, b_ih, b_hh, lin_W, lin_b, per_mod);
    }
    finish_kernel<<<1, 64, 0, stream>>>(per_mod, final_W, final_b, out);
}